// Round 4
// baseline (468.449 us; speedup 1.0000x reference)
//
#include <hip/hip_runtime.h>
#include <hip/hip_bf16.h>
#include <math.h>

typedef __attribute__((ext_vector_type(8))) short short8v;   // 8 bf16 (4 VGPR)
typedef __attribute__((ext_vector_type(4))) float float4v;   // 4 f32 acc

namespace {
constexpr int kBSZ = 16;
constexpr int kNW  = 1024;
constexpr int kT   = 3072;
constexpr int kBED = 128;
constexpr int kWED = 512;
constexpr int kR   = kBSZ * kT;    // 49152
constexpr int kMP  = kBSZ * kNW;   // 16384
}

// bf16 <-> f32 (RNE)
__device__ __forceinline__ unsigned short f2b(float x) {
  unsigned int u = __float_as_uint(x);
  u = u + 0x7FFFu + ((u >> 16) & 1u);
  return (unsigned short)(u >> 16);
}
__device__ __forceinline__ float b2f(unsigned short u) {
  return __uint_as_float(((unsigned int)u) << 16);
}

__device__ __forceinline__ void async16(void* l, const void* g) {
  __builtin_amdgcn_global_load_lds(
      (const __attribute__((address_space(1))) void*)g,
      (__attribute__((address_space(3))) void*)l, 16, 0, 0);
}

// Swizzle for 64-B LDS rows (BK=32): physical 16-B slot p of row r holds
// global chunk p ^ ((r>>1)&3). For fixed read-phase q over any 16
// consecutive rows, each bank-granule gets exactly 2 lanes -> conflict-free
// (verified round 3: SQ_LDS_BANK_CONFLICT == 0).
__device__ __forceinline__ int swz(int row) { return (row >> 1) & 3; }

// ---------------------------------------------------------------------------
// Embedding -> bf16 (kR, 128)
// ---------------------------------------------------------------------------
__global__ __launch_bounds__(256) void k_embed(
    const int* __restrict__ tok, const int* __restrict__ msk,
    const float* __restrict__ emb, unsigned short* __restrict__ out) {
  int idx = blockIdx.x * 256 + threadIdx.x;   // kR * 32
  int row = idx >> 5, c4 = idx & 31;
  const float4* e4 = (const float4*)emb;
  float4 a = e4[tok[row] * 32 + c4];
  float4 b = e4[(msk[row] ? 4 : 0) * 32 + c4];
  ushort4 o;
  o.x = f2b(a.x + b.x); o.y = f2b(a.y + b.y);
  o.z = f2b(a.z + b.z); o.w = f2b(a.w + b.w);
  ((ushort4*)out)[idx] = o;
}

// ---------------------------------------------------------------------------
// Merged weight prep (1 launch):
//   conv W (3,CIN,512) f32 -> (3,512,CIN) bf16 ; plain f32->bf16 for hw/proj
// ---------------------------------------------------------------------------
__global__ __launch_bounds__(256) void k_prep(
    const float* __restrict__ c0W, const float* __restrict__ c1W,
    const float* __restrict__ h0W, const float* __restrict__ h1W,
    const float* __restrict__ pW,
    unsigned short* __restrict__ cw0, unsigned short* __restrict__ cw1,
    unsigned short* __restrict__ hw0, unsigned short* __restrict__ hw1,
    unsigned short* __restrict__ pwb) {
  int idx = blockIdx.x * 256 + threadIdx.x;
  if (idx < 196608) {                      // cw0: 3*512*128
    int k = idx & 127, n = (idx >> 7) & 511, dt = idx >> 16;
    cw0[idx] = f2b(c0W[(long)(dt * 128 + k) * 512 + n]);
    return;
  }
  idx -= 196608;
  if (idx < 786432) {                      // cw1: 3*512*512
    int k = idx & 511, n = (idx >> 9) & 511, dt = idx >> 18;
    cw1[idx] = f2b(c1W[(long)(dt * 512 + k) * 512 + n]);
    return;
  }
  idx -= 786432;
  if (idx < 1048576) { hw0[idx] = f2b(h0W[idx]); return; }
  idx -= 1048576;
  if (idx < 1048576) { hw1[idx] = f2b(h1W[idx]); return; }
  idx -= 1048576;
  if (idx < 262144)  { pwb[idx] = f2b(pW[idx]); }
}

// ---------------------------------------------------------------------------
// Per-batch inclusive cumsum of pool_lengths (hoisted: GEMMs early-exit on it)
// ---------------------------------------------------------------------------
__global__ void k_cumsum(const int* __restrict__ pl, int* __restrict__ cum) {
  __shared__ int s[kNW];
  int b = blockIdx.x, i = threadIdx.x;
  s[i] = pl[b * kNW + i];
  __syncthreads();
  for (int off = 1; off < kNW; off <<= 1) {
    int cur = s[i];
    int add = (i >= off) ? s[i - off] : 0;
    __syncthreads();
    s[i] = cur + add;
    __syncthreads();
  }
  cum[b * kNW + i] = s[i];
}

// ---------------------------------------------------------------------------
// Conv1d as GEMM. 256x256 tile, 8 waves (2M x 4N), per-wave 128x64 = 8x4
// frags per tap -> 36 ds_read per 96 MFMA (0.375 KB/MFMA vs 0.5 before).
// BK=32, dbuf, issue-early stage, one __syncthreads per step.
// A: 258 swizzled 64-B rows (global t0-1 .. t0+256); halo via reg path.
// ---------------------------------------------------------------------------
template <int CIN, bool RESID>
__global__ __launch_bounds__(512, 2) void k_convm(
    const unsigned short* __restrict__ X,
    const unsigned short* __restrict__ Wt,
    const float* __restrict__ bias,
    const unsigned short* __restrict__ resid,
    const int* __restrict__ cum,
    unsigned short* __restrict__ out) {
  const int row0 = blockIdx.x * 256, n0 = blockIdx.y * 256;
  const int b = row0 / kT, t0 = row0 % kT;
  if (t0 >= cum[b * kNW + kNW - 1] + 2) return;   // early exit: dead rows

  constexpr int NT = CIN / 32;
  __shared__ short lds[2][(258 + 768) * 32];   // A[258][32] | B[768][32] x2
  const int tid = threadIdx.x, wv = tid >> 6, lane = tid & 63;
  const int q = lane >> 4, rr = lane & 15;
  const int dr = lane >> 2, sl = lane & 3;     // staging row-in-group, slot
  const bool lo_ok = (t0 > 0), hi_ok = (t0 + 256 < kT);
  const int wr = (wv >> 2) * 128, wc = (wv & 3) * 64;

  float4v acc[8][4] = {};
  short8v hv = {0, 0, 0, 0, 0, 0, 0, 0};       // halo prefetch (tid<8)
  const int hch = tid & 3;                     // swz(0)==swz(257)==0 -> linear
  const long hrow = (tid < 4) ? (long)(row0 - 1) : (long)(row0 + 256);
  const bool hok = (tid < 4) ? lo_ok : hi_ok;

  auto stage = [&](int nb, int k0) {
    short* As = lds[nb];
    short* Bs = lds[nb] + 258 * 32;
#pragma unroll
    for (int i = 0; i < 2; ++i) {              // A LDS rows 1..256
      int r = 1 + (wv + 8 * i) * 16 + dr;
      int ch = sl ^ swz(r);
      async16((char*)As + (1 + (wv + 8 * i) * 16) * 64,
              X + (long)(row0 + r - 1) * CIN + k0 + ch * 8);
    }
#pragma unroll
    for (int i = 0; i < 6; ++i) {              // B rows 0..767 (3 taps x 256)
      int br = (wv + 8 * i) * 16 + dr;
      int ch = sl ^ swz(br);
      int dt = br >> 8, n = br & 255;
      async16((char*)Bs + (wv + 8 * i) * 16 * 64,
              Wt + ((long)(dt * kWED + n0 + n)) * CIN + k0 + ch * 8);
    }
    if (tid < 8) {                             // halo rows 0,257 -> regs
      short8v v = {0, 0, 0, 0, 0, 0, 0, 0};
      if (hok) v = *(const short8v*)(X + hrow * CIN + k0 + hch * 8);
      hv = v;
    }
  };
  auto halo_write = [&](int nb) {
    if (tid < 8) {
      int r = (tid < 4) ? 0 : 257;
      *(short8v*)((char*)lds[nb] + r * 64 + hch * 16) = hv;
    }
  };

  stage(0, 0);
  halo_write(0);
  __syncthreads();

  for (int t = 0; t < NT; ++t) {
    const int cur = t & 1, nb = cur ^ 1;
    if (t + 1 < NT) stage(nb, (t + 1) * 32);   // issue-early
    __builtin_amdgcn_sched_barrier(0);
    const char* As = (const char*)lds[cur];
    const char* Bs = (const char*)(lds[cur] + 258 * 32);
#pragma unroll
    for (int dt = 0; dt < 3; ++dt) {
      short8v a[8], bb[4];
#pragma unroll
      for (int mf = 0; mf < 8; ++mf) {
        int ra = wr + rr + dt + mf * 16;
        a[mf] = *(const short8v*)(As + ra * 64 + ((q ^ swz(ra)) * 16));
      }
#pragma unroll
      for (int nf = 0; nf < 4; ++nf) {
        int rb = dt * 256 + wc + rr + nf * 16;
        bb[nf] = *(const short8v*)(Bs + rb * 64 + ((q ^ swz(rb)) * 16));
      }
#pragma unroll
      for (int mf = 0; mf < 8; ++mf)
#pragma unroll
        for (int nf = 0; nf < 4; ++nf)
          acc[mf][nf] = __builtin_amdgcn_mfma_f32_16x16x32_bf16(
              a[mf], bb[nf], acc[mf][nf], 0, 0, 0);
    }
    if (t + 1 < NT) halo_write(nb);
    __syncthreads();                           // single drain per step
  }

#pragma unroll
  for (int nf = 0; nf < 4; ++nf) {
    int col = n0 + wc + nf * 16 + rr;
    float bv = bias[col];
#pragma unroll
    for (int mf = 0; mf < 8; ++mf)
#pragma unroll
      for (int r = 0; r < 4; ++r) {
        long row = row0 + wr + mf * 16 + q * 4 + r;
        float y = fmaxf(acc[mf][nf][r] + bv, 0.f);
        if (RESID) y += b2f(resid[row * kWED + col]);
        out[row * kWED + col] = f2b(y);
      }
  }
}

// ---------------------------------------------------------------------------
// Highway layer. 256 rows x 128 cols (h AND g per wave): 8 waves 2M x 4N,
// per-wave 128 rows x 32 cols with acch[8][2] + accg[8][2] -> 12 ds_read
// per 32 MFMA. BK=32, dbuf, issue-early, one sync per step. LDS 2x32 KB.
// ---------------------------------------------------------------------------
__global__ __launch_bounds__(512, 2) void k_hw(
    const unsigned short* __restrict__ X,
    const unsigned short* __restrict__ Wb,
    const float* __restrict__ bias,
    const int* __restrict__ cum,
    unsigned short* __restrict__ out) {
  const int row0 = blockIdx.x * 256, n0 = blockIdx.y * 128;
  const int b = row0 / kT, t0 = row0 % kT;
  if (t0 >= cum[b * kNW + kNW - 1] + 2) return;   // early exit: dead rows

  __shared__ short lds[2][(256 + 256) * 32];   // A[256][32] | B[256][32] x2
  const int tid = threadIdx.x, wv = tid >> 6, lane = tid & 63;
  const int q = lane >> 4, rr = lane & 15;
  const int dr = lane >> 2, sl = lane & 3;
  const int wr = (wv >> 2) * 128, wc = (wv & 3) * 32;

  float4v acch[8][2] = {}, accg[8][2] = {};

  auto stage = [&](int nb, int k0) {
    short* As = lds[nb];
    short* Bs = lds[nb] + 256 * 32;
#pragma unroll
    for (int i = 0; i < 2; ++i) {              // A rows 0..255
      int r = (wv + 8 * i) * 16 + dr;
      int ch = sl ^ swz(r);
      async16((char*)As + (wv + 8 * i) * 16 * 64,
              X + (long)(row0 + r) * kWED + k0 + ch * 8);
    }
#pragma unroll
    for (int i = 0; i < 2; ++i) {              // B rows 0..255: h(128)|g(128)
      int br = (wv + 8 * i) * 16 + dr;
      int ch = sl ^ swz(br);
      int wrow = (br < 128) ? (n0 + br) : (512 + n0 + br - 128);
      async16((char*)Bs + (wv + 8 * i) * 16 * 64,
              Wb + (long)wrow * kWED + k0 + ch * 8);
    }
  };

  stage(0, 0);
  __syncthreads();

  for (int t = 0; t < 16; ++t) {
    const int cur = t & 1, nb = cur ^ 1;
    if (t + 1 < 16) stage(nb, (t + 1) * 32);
    __builtin_amdgcn_sched_barrier(0);
    const char* As = (const char*)lds[cur];
    const char* Bs = (const char*)(lds[cur] + 256 * 32);
    short8v a[8], bh[2], bg[2];
#pragma unroll
    for (int mf = 0; mf < 8; ++mf) {
      int ra = wr + rr + mf * 16;
      a[mf] = *(const short8v*)(As + ra * 64 + ((q ^ swz(ra)) * 16));
    }
#pragma unroll
    for (int nf = 0; nf < 2; ++nf) {
      int rh = wc + rr + nf * 16;
      int rg = 128 + rh;
      bh[nf] = *(const short8v*)(Bs + rh * 64 + ((q ^ swz(rh)) * 16));
      bg[nf] = *(const short8v*)(Bs + rg * 64 + ((q ^ swz(rg)) * 16));
    }
#pragma unroll
    for (int mf = 0; mf < 8; ++mf)
#pragma unroll
      for (int nf = 0; nf < 2; ++nf) {
        acch[mf][nf] = __builtin_amdgcn_mfma_f32_16x16x32_bf16(
            a[mf], bh[nf], acch[mf][nf], 0, 0, 0);
        accg[mf][nf] = __builtin_amdgcn_mfma_f32_16x16x32_bf16(
            a[mf], bg[nf], accg[mf][nf], 0, 0, 0);
      }
    __syncthreads();
  }

#pragma unroll
  for (int nf = 0; nf < 2; ++nf) {
    int col = n0 + wc + nf * 16 + rr;
    float bhv = bias[col], bgv = bias[512 + col];
#pragma unroll
    for (int mf = 0; mf < 8; ++mf)
#pragma unroll
      for (int r = 0; r < 4; ++r) {
        long row = row0 + wr + mf * 16 + q * 4 + r;
        float h = fmaxf(acch[mf][nf][r] + bhv, 0.f);
        float g = 1.f / (1.f + __expf(-(accg[mf][nf][r] + bgv)));
        float xv = b2f(X[row * kWED + col]);
        out[row * kWED + col] = f2b(g * h + (1.f - g) * xv);
      }
  }
}

// ---------------------------------------------------------------------------
// Projection: 256x256 tile, 8 waves, per-wave 128x64 = 8x4. BK=32, dbuf.
// ---------------------------------------------------------------------------
__global__ __launch_bounds__(512, 2) void k_proj(
    const unsigned short* __restrict__ A,
    const unsigned short* __restrict__ Wb,   // (512,512) [n][k] bf16
    const float* __restrict__ bias,
    float* __restrict__ out) {
  __shared__ short lds[2][(256 + 256) * 32];
  const int tid = threadIdx.x, wv = tid >> 6, lane = tid & 63;
  const int q = lane >> 4, rr = lane & 15;
  const int dr = lane >> 2, sl = lane & 3;
  const int row0 = blockIdx.x * 256, n0 = blockIdx.y * 256;
  const int wr = (wv >> 2) * 128, wc = (wv & 3) * 64;

  float4v acc[8][4] = {};

  auto stage = [&](int nb, int k0) {
    short* As = lds[nb];
    short* Bs = lds[nb] + 256 * 32;
#pragma unroll
    for (int i = 0; i < 2; ++i) {
      int r = (wv + 8 * i) * 16 + dr;
      int ch = sl ^ swz(r);
      async16((char*)As + (wv + 8 * i) * 16 * 64,
              A + (long)(row0 + r) * kWED + k0 + ch * 8);
    }
#pragma unroll
    for (int i = 0; i < 2; ++i) {
      int r = (wv + 8 * i) * 16 + dr;
      int ch = sl ^ swz(r);
      async16((char*)Bs + (wv + 8 * i) * 16 * 64,
              Wb + (long)(n0 + r) * kWED + k0 + ch * 8);
    }
  };

  stage(0, 0);
  __syncthreads();

  for (int t = 0; t < 16; ++t) {
    const int cur = t & 1, nb = cur ^ 1;
    if (t + 1 < 16) stage(nb, (t + 1) * 32);
    __builtin_amdgcn_sched_barrier(0);
    const char* As = (const char*)lds[cur];
    const char* Bs = (const char*)(lds[cur] + 256 * 32);
    short8v a[8], bb[4];
#pragma unroll
    for (int mf = 0; mf < 8; ++mf) {
      int ra = wr + rr + mf * 16;
      a[mf] = *(const short8v*)(As + ra * 64 + ((q ^ swz(ra)) * 16));
    }
#pragma unroll
    for (int nf = 0; nf < 4; ++nf) {
      int rb = wc + rr + nf * 16;
      bb[nf] = *(const short8v*)(Bs + rb * 64 + ((q ^ swz(rb)) * 16));
    }
#pragma unroll
    for (int mf = 0; mf < 8; ++mf)
#pragma unroll
      for (int nf = 0; nf < 4; ++nf)
        acc[mf][nf] = __builtin_amdgcn_mfma_f32_16x16x32_bf16(
            a[mf], bb[nf], acc[mf][nf], 0, 0, 0);
    __syncthreads();
  }

#pragma unroll
  for (int nf = 0; nf < 4; ++nf) {
    int col = n0 + wc + nf * 16 + rr;
    float bv = bias[col];
#pragma unroll
    for (int mf = 0; mf < 8; ++mf)
#pragma unroll
      for (int r = 0; r < 4; ++r) {
        long row = row0 + wr + mf * 16 + q * 4 + r;
        out[row * kWED + col] = acc[mf][nf][r] + bv;
      }
  }
}

// ---------------------------------------------------------------------------
__global__ __launch_bounds__(128) void k_pool(
    const unsigned short* __restrict__ x, const int* __restrict__ cum,
    unsigned short* __restrict__ pooled) {
  int bw = blockIdx.x;
  int b = bw >> 10, w = bw & 1023;
  int s = (w == 0) ? 0 : cum[bw - 1];
  int e = cum[bw];
  int c = threadIdx.x;
  float m0 = -INFINITY, m1 = -INFINITY, m2 = -INFINITY, m3 = -INFINITY;
  for (int t = s; t < e; ++t) {
    ushort4 v = ((const ushort4*)(x + (long)(b * kT + t) * kWED))[c];
    m0 = fmaxf(m0, b2f(v.x)); m1 = fmaxf(m1, b2f(v.y));
    m2 = fmaxf(m2, b2f(v.z)); m3 = fmaxf(m3, b2f(v.w));
  }
  if (e <= s) { m0 = m1 = m2 = m3 = 0.f; }
  ushort4 o;
  o.x = f2b(m0); o.y = f2b(m1); o.z = f2b(m2); o.w = f2b(m3);
  ((ushort4*)(pooled + (long)bw * kWED))[c] = o;
}

// ---------------------------------------------------------------------------
extern "C" void kernel_launch(void* const* d_in, const int* in_sizes, int n_in,
                              void* d_out, int out_size, void* d_ws, size_t ws_size,
                              hipStream_t stream) {
  (void)in_sizes; (void)n_in; (void)out_size; (void)ws_size;

  const int*   tok = (const int*)d_in[0];
  const int*   msk = (const int*)d_in[1];
  const int*   pl  = (const int*)d_in[2];
  const float* emb = (const float*)d_in[3];
  const float* c0W = (const float*)d_in[4];
  const float* c0b = (const float*)d_in[5];
  const float* c1W = (const float*)d_in[6];
  const float* c1b = (const float*)d_in[7];
  const float* h0W = (const float*)d_in[8];
  const float* h0b = (const float*)d_in[9];
  const float* h1W = (const float*)d_in[10];
  const float* h1b = (const float*)d_in[11];
  const float* pW  = (const float*)d_in[12];
  const float* pb  = (const float*)d_in[13];

  unsigned short* xb0 = (unsigned short*)d_ws;              // (kR,512) bf16
  unsigned short* xb1 = xb0 + (size_t)kR * kWED;            // (kR,512) bf16
  unsigned short* cw0 = xb1 + (size_t)kR * kWED;            // (3,512,128)
  unsigned short* cw1 = cw0 + 3 * kWED * kBED;              // (3,512,512)
  unsigned short* hw0 = cw1 + 3 * kWED * kWED;              // (2,1024,512)
  unsigned short* hw1 = hw0 + 2 * 1024 * kWED;
  unsigned short* pwb = hw1 + 2 * 1024 * kWED;              // (512,512)
  int* cum = (int*)(pwb + kWED * kWED);

  // cumsum first: GEMMs early-exit on src lengths
  k_cumsum<<<kBSZ, kNW, 0, stream>>>(pl, cum);

  // merged weight prep: 3342336 elements total
  k_prep<<<(3342336 + 255) / 256, 256, 0, stream>>>(
      c0W, c1W, h0W, h1W, pW, cw0, cw1, hw0, hw1, pwb);

  k_embed<<<kR * 32 / 256, 256, 0, stream>>>(tok, msk, emb, xb0);

  dim3 gc(kR / 256, kWED / 256);    // (192, 2) conv
  dim3 ghw(kR / 256, kWED / 128);   // (192, 4) highway
  dim3 gp(kMP / 256, kWED / 256);   // (64, 2)  proj

  k_convm<kBED, false><<<gc, 512, 0, stream>>>(xb0, cw0, c0b, nullptr, cum, xb1);
  k_hw<<<ghw, 512, 0, stream>>>(xb1, hw0, h0b, cum, xb0);
  k_hw<<<ghw, 512, 0, stream>>>(xb0, hw0 + 1024 * kWED, h0b + 1024, cum, xb1);
  k_convm<kWED, true><<<gc, 512, 0, stream>>>(xb1, cw1, c1b, xb1, cum, xb0);
  k_hw<<<ghw, 512, 0, stream>>>(xb0, hw1, h1b, cum, xb1);
  k_hw<<<ghw, 512, 0, stream>>>(xb1, hw1 + 1024 * kWED, h1b + 1024, cum, xb0);

  k_pool<<<kMP, 128, 0, stream>>>(xb0, cum, xb1);

  k_proj<<<gp, 512, 0, stream>>>(xb1, pwb, pb, (float*)d_out);
}

// Round 5
// 398.388 us; speedup vs baseline: 1.1759x; 1.1759x over previous
//
#include <hip/hip_runtime.h>
#include <hip/hip_bf16.h>
#include <math.h>

typedef __attribute__((ext_vector_type(8))) short short8v;   // 8 bf16 (4 VGPR)
typedef __attribute__((ext_vector_type(4))) float float4v;   // 4 f32 acc

#define VMCNT(n) asm volatile("s_waitcnt vmcnt(" #n ")" ::: "memory")
#define LGK0     asm volatile("s_waitcnt lgkmcnt(0)" ::: "memory")

namespace {
constexpr int kBSZ = 16;
constexpr int kNW  = 1024;
constexpr int kT   = 3072;
constexpr int kBED = 128;
constexpr int kWED = 512;
constexpr int kR   = kBSZ * kT;    // 49152
constexpr int kMP  = kBSZ * kNW;   // 16384
}

// bf16 <-> f32 (RNE)
__device__ __forceinline__ unsigned short f2b(float x) {
  unsigned int u = __float_as_uint(x);
  u = u + 0x7FFFu + ((u >> 16) & 1u);
  return (unsigned short)(u >> 16);
}
__device__ __forceinline__ float b2f(unsigned short u) {
  return __uint_as_float(((unsigned int)u) << 16);
}

__device__ __forceinline__ void async16(void* l, const void* g) {
  __builtin_amdgcn_global_load_lds(
      (const __attribute__((address_space(1))) void*)g,
      (__attribute__((address_space(3))) void*)l, 16, 0, 0);
}

// Swizzle for 64-B LDS rows (BK=32): physical 16-B slot p of row r holds
// global chunk p ^ ((r>>1)&3). Verified round 3: SQ_LDS_BANK_CONFLICT == 0.
__device__ __forceinline__ int swz(int row) { return (row >> 1) & 3; }

// ---------------------------------------------------------------------------
// Embedding -> bf16 (kR, 128)
// ---------------------------------------------------------------------------
__global__ __launch_bounds__(256) void k_embed(
    const int* __restrict__ tok, const int* __restrict__ msk,
    const float* __restrict__ emb, unsigned short* __restrict__ out) {
  int idx = blockIdx.x * 256 + threadIdx.x;   // kR * 32
  int row = idx >> 5, c4 = idx & 31;
  const float4* e4 = (const float4*)emb;
  float4 a = e4[tok[row] * 32 + c4];
  float4 b = e4[(msk[row] ? 4 : 0) * 32 + c4];
  ushort4 o;
  o.x = f2b(a.x + b.x); o.y = f2b(a.y + b.y);
  o.z = f2b(a.z + b.z); o.w = f2b(a.w + b.w);
  ((ushort4*)out)[idx] = o;
}

// ---------------------------------------------------------------------------
// Merged weight prep (1 launch):
//   conv W (3,CIN,512) f32 -> (3,512,CIN) bf16 ; plain f32->bf16 for hw/proj
// ---------------------------------------------------------------------------
__global__ __launch_bounds__(256) void k_prep(
    const float* __restrict__ c0W, const float* __restrict__ c1W,
    const float* __restrict__ h0W, const float* __restrict__ h1W,
    const float* __restrict__ pW,
    unsigned short* __restrict__ cw0, unsigned short* __restrict__ cw1,
    unsigned short* __restrict__ hw0, unsigned short* __restrict__ hw1,
    unsigned short* __restrict__ pwb) {
  int idx = blockIdx.x * 256 + threadIdx.x;
  if (idx < 196608) {                      // cw0: 3*512*128
    int k = idx & 127, n = (idx >> 7) & 511, dt = idx >> 16;
    cw0[idx] = f2b(c0W[(long)(dt * 128 + k) * 512 + n]);
    return;
  }
  idx -= 196608;
  if (idx < 786432) {                      // cw1: 3*512*512
    int k = idx & 511, n = (idx >> 9) & 511, dt = idx >> 18;
    cw1[idx] = f2b(c1W[(long)(dt * 512 + k) * 512 + n]);
    return;
  }
  idx -= 786432;
  if (idx < 1048576) { hw0[idx] = f2b(h0W[idx]); return; }
  idx -= 1048576;
  if (idx < 1048576) { hw1[idx] = f2b(h1W[idx]); return; }
  idx -= 1048576;
  if (idx < 262144)  { pwb[idx] = f2b(pW[idx]); }
}

// ---------------------------------------------------------------------------
// Per-batch inclusive cumsum of pool_lengths (hoisted: GEMMs early-exit on it)
// ---------------------------------------------------------------------------
__global__ void k_cumsum(const int* __restrict__ pl, int* __restrict__ cum) {
  __shared__ int s[kNW];
  int b = blockIdx.x, i = threadIdx.x;
  s[i] = pl[b * kNW + i];
  __syncthreads();
  for (int off = 1; off < kNW; off <<= 1) {
    int cur = s[i];
    int add = (i >= off) ? s[i - off] : 0;
    __syncthreads();
    s[i] = cur + add;
    __syncthreads();
  }
  cum[b * kNW + i] = s[i];
}

// ---------------------------------------------------------------------------
// Conv1d as GEMM (unchanged round-3 form: 128x128, BK=32, dbuf, swizzled).
// ---------------------------------------------------------------------------
template <int CIN, bool RESID>
__global__ __launch_bounds__(256, 2) void k_convm(
    const unsigned short* __restrict__ X,
    const unsigned short* __restrict__ Wt,
    const float* __restrict__ bias,
    const unsigned short* __restrict__ resid,
    const int* __restrict__ cum,
    unsigned short* __restrict__ out) {
  const int row0 = blockIdx.x * 128, n0 = blockIdx.y * 128;
  const int b = row0 / kT, t0 = row0 % kT;
  if (t0 >= cum[b * kNW + kNW - 1] + 2) return;   // early exit: dead rows

  constexpr int NT = CIN / 32;
  __shared__ short lds[2][(130 + 384) * 32];   // A[130][32] | B[384][32] x2
  const int tid = threadIdx.x, wave = tid >> 6, lane = tid & 63;
  const int q = lane >> 4, rr = lane & 15;
  const int dr = lane >> 2, sl = lane & 3;     // staging row-in-group, slot
  const bool lo_ok = (t0 > 0), hi_ok = (t0 + 128 < kT);
  const int wr = (wave >> 1) * 64, wc = (wave & 1) * 64;

  float4v acc[4][4] = {};
  short8v hv = {0, 0, 0, 0, 0, 0, 0, 0};       // halo prefetch (tid<8)
  const int hch = tid & 3;
  const long hrow = (tid < 4) ? (long)(row0 - 1) : (long)(row0 + 128);
  const bool hok = (tid < 4) ? lo_ok : hi_ok;

  auto stage = [&](int nb, int k0) {
    short* As = lds[nb];
    short* Bs = lds[nb] + 130 * 32;
#pragma unroll
    for (int i = 0; i < 2; ++i) {              // A LDS rows 1..128
      int r0 = (wave + 4 * i) * 16;
      int ch = sl ^ swz(1 + r0 + dr);
      async16((char*)As + (1 + r0) * 64,
              X + (long)(row0 + r0 + dr) * CIN + k0 + ch * 8);
    }
#pragma unroll
    for (int i = 0; i < 6; ++i) {              // B rows 0..383
      int r0 = (wave + 4 * i) * 16;
      int br = r0 + dr;
      int ch = sl ^ swz(br);
      int dt = br >> 7, n = br & 127;
      async16((char*)Bs + r0 * 64,
              Wt + ((long)(dt * kWED + n0 + n)) * CIN + k0 + ch * 8);
    }
    if (tid < 8) {                             // halo rows 0,129 -> regs
      short8v v = {0, 0, 0, 0, 0, 0, 0, 0};
      if (hok) v = *(const short8v*)(X + hrow * CIN + k0 + hch * 8);
      hv = v;
    }
  };
  auto halo_write = [&](int nb) {
    if (tid < 8) {
      int r = (tid < 4) ? 0 : 129;
      *(short8v*)((char*)lds[nb] + r * 64 + hch * 16) = hv;
    }
  };

  stage(0, 0);
  halo_write(0);
  __syncthreads();

  for (int t = 0; t < NT; ++t) {
    const int cur = t & 1, nb = cur ^ 1;
    if (t + 1 < NT) stage(nb, (t + 1) * 32);   // issue-early
    __builtin_amdgcn_sched_barrier(0);
    const char* As = (const char*)lds[cur];
    const char* Bs = (const char*)(lds[cur] + 130 * 32);
#pragma unroll
    for (int dt = 0; dt < 3; ++dt) {
      short8v a[4], bb[4];
#pragma unroll
      for (int mf = 0; mf < 4; ++mf) {
        int ra = wr + rr + dt + mf * 16;
        a[mf] = *(const short8v*)(As + ra * 64 + ((q ^ swz(ra)) * 16));
      }
#pragma unroll
      for (int nf = 0; nf < 4; ++nf) {
        int rb = dt * 128 + wc + rr + nf * 16;
        bb[nf] = *(const short8v*)(Bs + rb * 64 + ((q ^ swz(rb)) * 16));
      }
#pragma unroll
      for (int mf = 0; mf < 4; ++mf)
#pragma unroll
        for (int nf = 0; nf < 4; ++nf)
          acc[mf][nf] = __builtin_amdgcn_mfma_f32_16x16x32_bf16(
              a[mf], bb[nf], acc[mf][nf], 0, 0, 0);
    }
    if (t + 1 < NT) halo_write(nb);
    __syncthreads();                           // single drain per step
  }

#pragma unroll
  for (int nf = 0; nf < 4; ++nf) {
    int col = n0 + wc + nf * 16 + rr;
    float bv = bias[col];
#pragma unroll
    for (int mf = 0; mf < 4; ++mf)
#pragma unroll
      for (int r = 0; r < 4; ++r) {
        long row = row0 + wr + mf * 16 + q * 4 + r;
        float y = fmaxf(acc[mf][nf][r] + bv, 0.f);
        if (RESID) y += b2f(resid[row * kWED + col]);
        out[row * kWED + col] = f2b(y);
      }
  }
}

// ---------------------------------------------------------------------------
// Highway layer: 3-buffer depth-2 counted-vmcnt pipeline. 128x128, BK=32,
// swizzled (0 conflicts, r3). Per step: ds_read frags(buf t) -> issue
// stage(t+2) -> lgkm0 -> MFMA -> vmcnt(6) [forces t+1 landed, t+2 stays in
// flight; NEVER 0 in loop] -> s_barrier. LDS 3x24 KB -> 2 blocks/CU.
// WAR safety: buf (t+2)%3's readers (step t-1) finished before barrier(t).
// ---------------------------------------------------------------------------
__global__ __launch_bounds__(256, 2) void k_hw(
    const unsigned short* __restrict__ X,
    const unsigned short* __restrict__ Wb,
    const float* __restrict__ bias,
    const int* __restrict__ cum,
    unsigned short* __restrict__ out) {
  const int row0 = blockIdx.x * 128, n0 = blockIdx.y * 128;
  const int b = row0 / kT, t0 = row0 % kT;
  if (t0 >= cum[b * kNW + kNW - 1] + 2) return;   // early exit: dead rows

  __shared__ short lds[3][(128 + 256) * 32];   // A[128][32] | B[256][32] x3
  const int tid = threadIdx.x, wave = tid >> 6, lane = tid & 63;
  const int q = lane >> 4, rr = lane & 15;
  const int dr = lane >> 2, sl = lane & 3;
  const int wr = (wave >> 1) * 64, wc = (wave & 1) * 64;

  float4v acch[4][4] = {}, accg[4][4] = {};

  auto stage = [&](int nb, int k0) {           // 6 loads/thread
    short* As = lds[nb];
    short* Bs = lds[nb] + 128 * 32;
#pragma unroll
    for (int i = 0; i < 2; ++i) {              // A rows 0..127
      int r0 = (wave + 4 * i) * 16;
      int ch = sl ^ swz(r0 + dr);
      async16((char*)As + r0 * 64,
              X + (long)(row0 + r0 + dr) * kWED + k0 + ch * 8);
    }
#pragma unroll
    for (int i = 0; i < 4; ++i) {              // B rows 0..255 (h then g)
      int r0 = (wave + 4 * i) * 16;
      int br = r0 + dr;
      int ch = sl ^ swz(br);
      int g = br >> 7, n = br & 127;
      async16((char*)Bs + r0 * 64,
              Wb + ((long)(g * 512 + n0 + n)) * kWED + k0 + ch * 8);
    }
  };

  // prologue: buffers 0,1 in flight; force buf0 landed (vmcnt(6) leaves buf1)
  stage(0, 0);
  stage(1, 32);
  VMCNT(6);
  __builtin_amdgcn_s_barrier();
  __builtin_amdgcn_sched_barrier(0);

  for (int t = 0; t < 16; ++t) {
    const char* As = (const char*)lds[t % 3];
    const char* Bs = (const char*)(lds[t % 3] + 128 * 32);
    short8v a[4], bh[4], bg[4];
#pragma unroll
    for (int mf = 0; mf < 4; ++mf) {
      int ra = wr + rr + mf * 16;
      a[mf] = *(const short8v*)(As + ra * 64 + ((q ^ swz(ra)) * 16));
    }
#pragma unroll
    for (int nf = 0; nf < 4; ++nf) {
      int rh = wc + rr + nf * 16;
      int rg = 128 + rh;
      bh[nf] = *(const short8v*)(Bs + rh * 64 + ((q ^ swz(rh)) * 16));
      bg[nf] = *(const short8v*)(Bs + rg * 64 + ((q ^ swz(rg)) * 16));
    }
    if (t + 2 < 16) stage((t + 2) % 3, (t + 2) * 32);
    LGK0; __builtin_amdgcn_sched_barrier(0);
#pragma unroll
    for (int mf = 0; mf < 4; ++mf)
#pragma unroll
      for (int nf = 0; nf < 4; ++nf) {
        acch[mf][nf] = __builtin_amdgcn_mfma_f32_16x16x32_bf16(
            a[mf], bh[nf], acch[mf][nf], 0, 0, 0);
        accg[mf][nf] = __builtin_amdgcn_mfma_f32_16x16x32_bf16(
            a[mf], bg[nf], accg[mf][nf], 0, 0, 0);
      }
    if (t + 2 < 16) { VMCNT(6); } else { VMCNT(0); }
    __builtin_amdgcn_s_barrier();
    __builtin_amdgcn_sched_barrier(0);
  }

#pragma unroll
  for (int nf = 0; nf < 4; ++nf) {
    int col = n0 + wc + nf * 16 + rr;
    float bhv = bias[col], bgv = bias[512 + col];
#pragma unroll
    for (int mf = 0; mf < 4; ++mf)
#pragma unroll
      for (int r = 0; r < 4; ++r) {
        long row = row0 + wr + mf * 16 + q * 4 + r;
        float h = fmaxf(acch[mf][nf][r] + bhv, 0.f);
        float g = 1.f / (1.f + __expf(-(accg[mf][nf][r] + bgv)));
        float xv = b2f(X[row * kWED + col]);
        out[row * kWED + col] = f2b(g * h + (1.f - g) * xv);
      }
  }
}

// ---------------------------------------------------------------------------
// Projection: same 3-buffer counted-vmcnt pipeline (4 loads/thread/step).
// ---------------------------------------------------------------------------
__global__ __launch_bounds__(256, 2) void k_proj(
    const unsigned short* __restrict__ A,
    const unsigned short* __restrict__ Wb,   // (512,512) [n][k] bf16
    const float* __restrict__ bias,
    float* __restrict__ out) {
  __shared__ short lds[3][(128 + 128) * 32];
  const int tid = threadIdx.x, wave = tid >> 6, lane = tid & 63;
  const int q = lane >> 4, rr = lane & 15;
  const int dr = lane >> 2, sl = lane & 3;
  const int row0 = blockIdx.x * 128, n0 = blockIdx.y * 128;
  const int wr = (wave >> 1) * 64, wc = (wave & 1) * 64;

  float4v acc[4][4] = {};

  auto stage = [&](int nb, int k0) {           // 4 loads/thread
    short* As = lds[nb];
    short* Bs = lds[nb] + 128 * 32;
#pragma unroll
    for (int i = 0; i < 2; ++i) {
      int r0 = (wave + 4 * i) * 16;
      int ch = sl ^ swz(r0 + dr);
      async16((char*)As + r0 * 64,
              A + (long)(row0 + r0 + dr) * kWED + k0 + ch * 8);
    }
#pragma unroll
    for (int i = 0; i < 2; ++i) {
      int r0 = (wave + 4 * i) * 16;
      int ch = sl ^ swz(r0 + dr);
      async16((char*)Bs + r0 * 64,
              Wb + (long)(n0 + r0 + dr) * kWED + k0 + ch * 8);
    }
  };

  stage(0, 0);
  stage(1, 32);
  VMCNT(4);
  __builtin_amdgcn_s_barrier();
  __builtin_amdgcn_sched_barrier(0);

  for (int t = 0; t < 16; ++t) {
    const char* As = (const char*)lds[t % 3];
    const char* Bs = (const char*)(lds[t % 3] + 128 * 32);
    short8v a[4], bb[4];
#pragma unroll
    for (int mf = 0; mf < 4; ++mf) {
      int ra = wr + rr + mf * 16;
      a[mf] = *(const short8v*)(As + ra * 64 + ((q ^ swz(ra)) * 16));
    }
#pragma unroll
    for (int nf = 0; nf < 4; ++nf) {
      int rb = wc + rr + nf * 16;
      bb[nf] = *(const short8v*)(Bs + rb * 64 + ((q ^ swz(rb)) * 16));
    }
    if (t + 2 < 16) stage((t + 2) % 3, (t + 2) * 32);
    LGK0; __builtin_amdgcn_sched_barrier(0);
#pragma unroll
    for (int mf = 0; mf < 4; ++mf)
#pragma unroll
      for (int nf = 0; nf < 4; ++nf)
        acc[mf][nf] = __builtin_amdgcn_mfma_f32_16x16x32_bf16(
            a[mf], bb[nf], acc[mf][nf], 0, 0, 0);
    if (t + 2 < 16) { VMCNT(4); } else { VMCNT(0); }
    __builtin_amdgcn_s_barrier();
    __builtin_amdgcn_sched_barrier(0);
  }

#pragma unroll
  for (int nf = 0; nf < 4; ++nf) {
    int col = n0 + wc + nf * 16 + rr;
    float bv = bias[col];
#pragma unroll
    for (int mf = 0; mf < 4; ++mf)
#pragma unroll
      for (int r = 0; r < 4; ++r) {
        long row = row0 + wr + mf * 16 + q * 4 + r;
        out[row * kWED + col] = acc[mf][nf][r] + bv;
      }
  }
}

// ---------------------------------------------------------------------------
__global__ __launch_bounds__(128) void k_pool(
    const unsigned short* __restrict__ x, const int* __restrict__ cum,
    unsigned short* __restrict__ pooled) {
  int bw = blockIdx.x;
  int b = bw >> 10, w = bw & 1023;
  int s = (w == 0) ? 0 : cum[bw - 1];
  int e = cum[bw];
  int c = threadIdx.x;
  float m0 = -INFINITY, m1 = -INFINITY, m2 = -INFINITY, m3 = -INFINITY;
  for (int t = s; t < e; ++t) {
    ushort4 v = ((const ushort4*)(x + (long)(b * kT + t) * kWED))[c];
    m0 = fmaxf(m0, b2f(v.x)); m1 = fmaxf(m1, b2f(v.y));
    m2 = fmaxf(m2, b2f(v.z)); m3 = fmaxf(m3, b2f(v.w));
  }
  if (e <= s) { m0 = m1 = m2 = m3 = 0.f; }
  ushort4 o;
  o.x = f2b(m0); o.y = f2b(m1); o.z = f2b(m2); o.w = f2b(m3);
  ((ushort4*)(pooled + (long)bw * kWED))[c] = o;
}

// ---------------------------------------------------------------------------
extern "C" void kernel_launch(void* const* d_in, const int* in_sizes, int n_in,
                              void* d_out, int out_size, void* d_ws, size_t ws_size,
                              hipStream_t stream) {
  (void)in_sizes; (void)n_in; (void)out_size; (void)ws_size;

  const int*   tok = (const int*)d_in[0];
  const int*   msk = (const int*)d_in[1];
  const int*   pl  = (const int*)d_in[2];
  const float* emb = (const float*)d_in[3];
  const float* c0W = (const float*)d_in[4];
  const float* c0b = (const float*)d_in[5];
  const float* c1W = (const float*)d_in[6];
  const float* c1b = (const float*)d_in[7];
  const float* h0W = (const float*)d_in[8];
  const float* h0b = (const float*)d_in[9];
  const float* h1W = (const float*)d_in[10];
  const float* h1b = (const float*)d_in[11];
  const float* pW  = (const float*)d_in[12];
  const float* pb  = (const float*)d_in[13];

  unsigned short* xb0 = (unsigned short*)d_ws;              // (kR,512) bf16
  unsigned short* xb1 = xb0 + (size_t)kR * kWED;            // (kR,512) bf16
  unsigned short* cw0 = xb1 + (size_t)kR * kWED;            // (3,512,128)
  unsigned short* cw1 = cw0 + 3 * kWED * kBED;              // (3,512,512)
  unsigned short* hw0 = cw1 + 3 * kWED * kWED;              // (2,1024,512)
  unsigned short* hw1 = hw0 + 2 * 1024 * kWED;
  unsigned short* pwb = hw1 + 2 * 1024 * kWED;              // (512,512)
  int* cum = (int*)(pwb + kWED * kWED);

  // cumsum first: GEMMs early-exit on src lengths
  k_cumsum<<<kBSZ, kNW, 0, stream>>>(pl, cum);

  // merged weight prep: 3342336 elements total
  k_prep<<<(3342336 + 255) / 256, 256, 0, stream>>>(
      c0W, c1W, h0W, h1W, pW, cw0, cw1, hw0, hw1, pwb);

  k_embed<<<kR * 32 / 256, 256, 0, stream>>>(tok, msk, emb, xb0);

  dim3 g1(kR / 128, kWED / 128);   // (384, 4)

  k_convm<kBED, false><<<g1, 256, 0, stream>>>(xb0, cw0, c0b, nullptr, cum, xb1);
  k_hw<<<g1, 256, 0, stream>>>(xb1, hw0, h0b, cum, xb0);
  k_hw<<<g1, 256, 0, stream>>>(xb0, hw0 + 1024 * kWED, h0b + 1024, cum, xb1);
  k_convm<kWED, true><<<g1, 256, 0, stream>>>(xb1, cw1, c1b, xb1, cum, xb0);
  k_hw<<<g1, 256, 0, stream>>>(xb0, hw1, h1b, cum, xb1);
  k_hw<<<g1, 256, 0, stream>>>(xb1, hw1 + 1024 * kWED, h1b + 1024, cum, xb0);

  k_pool<<<kMP, 128, 0, stream>>>(xb0, cum, xb1);

  dim3 g2(kMP / 128, kWED / 128);  // (128, 4)
  k_proj<<<g2, 256, 0, stream>>>(xb1, pwb, pb, (float*)d_out);
}